// Round 2
// baseline (177.569 us; speedup 1.0000x reference)
//
#include <hip/hip_runtime.h>

#define BS 256
#define HS 512
#define IN_DIM 64
#define OUT_DIM 4

// ---------------------------------------------------------------------------
// Kernel 1: rec[b,i] = sum_j hidden[b,j] * (w[i,j] + alpha[i,j]*hebb[b,i,j])
// One wave (64 lanes) per (b,i) row of 512 elements; float4 loads; shfl reduce.
// ---------------------------------------------------------------------------
__global__ __launch_bounds__(256) void rec_kernel(
    const float* __restrict__ hidden,
    const float* __restrict__ hebb,
    const float* __restrict__ w,
    const float* __restrict__ alpha,
    float* __restrict__ rec)
{
    const int row  = blockIdx.x * 4 + (threadIdx.x >> 6);   // 4 waves per block
    const int lane = threadIdx.x & 63;
    const int b = row >> 9;          // row / HS
    const int i = row & (HS - 1);    // row % HS

    const float4* __restrict__ hebb4 = (const float4*)(hebb + (size_t)row * HS);
    const float4* __restrict__ w4    = (const float4*)(w     + (size_t)i * HS);
    const float4* __restrict__ a4    = (const float4*)(alpha + (size_t)i * HS);
    const float4* __restrict__ h4    = (const float4*)(hidden + (size_t)b * HS);

    float sum = 0.f;
#pragma unroll
    for (int t = 0; t < 2; ++t) {                 // 128 float4s per row / 64 lanes
        const int idx = lane + t * 64;
        const float4 hb = hebb4[idx];
        const float4 ww = w4[idx];
        const float4 aa = a4[idx];
        const float4 hh = h4[idx];
        sum += hh.x * (ww.x + aa.x * hb.x);
        sum += hh.y * (ww.y + aa.y * hb.y);
        sum += hh.z * (ww.z + aa.z * hb.z);
        sum += hh.w * (ww.w + aa.w * hb.w);
    }
#pragma unroll
    for (int off = 32; off > 0; off >>= 1)
        sum += __shfl_xor(sum, off, 64);
    if (lane == 0) rec[row] = sum;
}

// ---------------------------------------------------------------------------
// Kernel 2: per batch element b (one block of 512 threads, thread i = unit i):
//   hactiv[b,i] = tanh(inputs[b,:]@Wi[i,:] + bi[i] + rec[b,i])
//   activout[b,:], valueout[b], DAout[b] via block reductions
//   scale[b,i] = DAout[b] * hactiv[b,i]   (for the hebb update kernel)
// ---------------------------------------------------------------------------
__global__ __launch_bounds__(512) void act_kernel(
    const float* __restrict__ inputs,
    const float* __restrict__ Wi, const float* __restrict__ bi,
    const float* __restrict__ rec,
    const float* __restrict__ Wo, const float* __restrict__ bo,
    const float* __restrict__ Wv, const float* __restrict__ bv,
    const float* __restrict__ Wda, const float* __restrict__ bda,
    float* __restrict__ activout, float* __restrict__ valueout,
    float* __restrict__ daout, float* __restrict__ hactiv,
    float* __restrict__ scale)
{
    const int b = blockIdx.x;
    const int i = threadIdx.x;

    __shared__ __align__(16) float sh_in[IN_DIM];
    __shared__ float red[8][8];       // [wave][6 partial sums]
    __shared__ float da_sh;

    if (i < IN_DIM) sh_in[i] = inputs[b * IN_DIM + i];
    __syncthreads();

    // inputs[b,:] @ Wi[i,:]
    float dot = 0.f;
    const float4* __restrict__ wi4 = (const float4*)(Wi + (size_t)i * IN_DIM);
    const float4* __restrict__ in4 = (const float4*)sh_in;
#pragma unroll
    for (int t = 0; t < IN_DIM / 4; ++t) {
        const float4 a = wi4[t];
        const float4 x = in4[t];
        dot += a.x * x.x + a.y * x.y + a.z * x.z + a.w * x.w;
    }

    const float h = tanhf(dot + bi[i] + rec[(size_t)b * HS + i]);
    hactiv[(size_t)b * HS + i] = h;

    // six reductions over i: Wo rows 0..3, Wv, Wda
    float p[6];
    p[0] = h * Wo[0 * HS + i];
    p[1] = h * Wo[1 * HS + i];
    p[2] = h * Wo[2 * HS + i];
    p[3] = h * Wo[3 * HS + i];
    p[4] = h * Wv[i];
    p[5] = h * Wda[i];

    const int lane = i & 63, wave = i >> 6;
#pragma unroll
    for (int k = 0; k < 6; ++k) {
        float s = p[k];
#pragma unroll
        for (int off = 32; off > 0; off >>= 1)
            s += __shfl_xor(s, off, 64);
        if (lane == 0) red[wave][k] = s;
    }
    __syncthreads();

    if (i < 6) {
        float s = 0.f;
#pragma unroll
        for (int wv = 0; wv < 8; ++wv) s += red[wv][i];
        if (i < 4) {
            activout[b * OUT_DIM + i] = s + bo[i];
        } else if (i == 4) {
            valueout[b] = s + bv[0];
        } else {
            const float da = tanhf(s + bda[0]);
            daout[b] = da;
            da_sh = da;
        }
    }
    __syncthreads();

    scale[(size_t)b * HS + i] = da_sh * h;
}

// ---------------------------------------------------------------------------
// Kernel 3: hebb_new[b,i,j] = clip(hebb[b,i,j] + scale[b,i]*hidden[b,j], -1, 1)
// Pure streaming, float4 grid-stride.
// ---------------------------------------------------------------------------
__global__ __launch_bounds__(256) void hebb_kernel(
    const float* __restrict__ hebb,
    const float* __restrict__ hidden,
    const float* __restrict__ scale,
    float* __restrict__ hebb_new)
{
    const size_t total4 = (size_t)BS * HS * HS / 4;    // 16,777,216
    const size_t stride = (size_t)gridDim.x * blockDim.x;
    for (size_t v = (size_t)blockIdx.x * blockDim.x + threadIdx.x; v < total4; v += stride) {
        const size_t e = v * 4;
        const int b = (int)(e >> 18);            // / (HS*HS)
        const int i = (int)(e >> 9) & (HS - 1);  // / HS % HS
        const int j = (int)e & (HS - 1);         // % HS (multiple of 4)

        const float s = scale[b * HS + i];
        const float4 hid = *(const float4*)(hidden + b * HS + j);
        const float4 hb  = ((const float4*)hebb)[v];
        float4 o;
        o.x = fminf(fmaxf(hb.x + s * hid.x, -1.f), 1.f);
        o.y = fminf(fmaxf(hb.y + s * hid.y, -1.f), 1.f);
        o.z = fminf(fmaxf(hb.z + s * hid.z, -1.f), 1.f);
        o.w = fminf(fmaxf(hb.w + s * hid.w, -1.f), 1.f);
        ((float4*)hebb_new)[v] = o;
    }
}

extern "C" void kernel_launch(void* const* d_in, const int* in_sizes, int n_in,
                              void* d_out, int out_size, void* d_ws, size_t ws_size,
                              hipStream_t stream) {
    const float* inputs = (const float*)d_in[0];
    const float* hidden = (const float*)d_in[1];
    const float* hebb   = (const float*)d_in[2];
    const float* Wi     = (const float*)d_in[3];
    const float* bi     = (const float*)d_in[4];
    const float* w      = (const float*)d_in[5];
    const float* alpha  = (const float*)d_in[6];
    const float* Wo     = (const float*)d_in[7];
    const float* bo     = (const float*)d_in[8];
    const float* Wv     = (const float*)d_in[9];
    const float* bv     = (const float*)d_in[10];
    const float* Wda    = (const float*)d_in[11];
    const float* bda    = (const float*)d_in[12];

    float* out = (float*)d_out;
    float* activout = out;                       // [256,4]   = 1024
    float* valueout = out + 1024;                // [256,1]   = 256
    float* daout    = out + 1280;                // [256,1]   = 256
    float* hactiv   = out + 1536;                // [256,512] = 131072
    float* hebb_new = out + 1536 + BS * HS;      // [256,512,512]

    // workspace: rec and scale share the same 512 KB buffer (rec is consumed
    // by the same thread that later writes scale at the same index)
    float* rec   = (float*)d_ws;
    float* scale = rec;

    // Kernel 1: 131072 rows, 4 waves/block
    rec_kernel<<<(BS * HS) / 4, 256, 0, stream>>>(hidden, hebb, w, alpha, rec);

    // Kernel 2: one block per batch element
    act_kernel<<<BS, HS, 0, stream>>>(inputs, Wi, bi, rec, Wo, bo, Wv, bv,
                                      Wda, bda, activout, valueout, daout,
                                      hactiv, scale);

    // Kernel 3: streaming hebb update
    hebb_kernel<<<2048, 256, 0, stream>>>(hebb, hidden, scale, hebb_new);
}

// Round 5
// 138.519 us; speedup vs baseline: 1.2819x; 1.2819x over previous
//
#include <hip/hip_runtime.h>

#define BS 256
#define HS 512
#define IN_DIM 64
#define OUT_DIM 4

typedef float nfloat4 __attribute__((ext_vector_type(4)));  // native vec for nt builtins

// ---------------------------------------------------------------------------
// Kernel 1: rec[b,i] = sum_j hidden[b,j] * (w[i,j] + alpha[i,j]*hebb[b,i,j])
// One wave (64 lanes) per (b,i) row of 512 elements; float4 loads; shfl reduce.
// Forward traversal: leaves the TAIL of hebb resident in L3 for kernel 3.
// ---------------------------------------------------------------------------
__global__ __launch_bounds__(256) void rec_kernel(
    const float* __restrict__ hidden,
    const float* __restrict__ hebb,
    const float* __restrict__ w,
    const float* __restrict__ alpha,
    float* __restrict__ rec)
{
    const int row  = blockIdx.x * 4 + (threadIdx.x >> 6);   // 4 waves per block
    const int lane = threadIdx.x & 63;
    const int b = row >> 9;          // row / HS
    const int i = row & (HS - 1);    // row % HS

    const float4* __restrict__ hebb4 = (const float4*)(hebb + (size_t)row * HS);
    const float4* __restrict__ w4    = (const float4*)(w     + (size_t)i * HS);
    const float4* __restrict__ a4    = (const float4*)(alpha + (size_t)i * HS);
    const float4* __restrict__ h4    = (const float4*)(hidden + (size_t)b * HS);

    float sum = 0.f;
#pragma unroll
    for (int t = 0; t < 2; ++t) {                 // 128 float4s per row / 64 lanes
        const int idx = lane + t * 64;
        const float4 hb = hebb4[idx];
        const float4 ww = w4[idx];
        const float4 aa = a4[idx];
        const float4 hh = h4[idx];
        sum += hh.x * (ww.x + aa.x * hb.x);
        sum += hh.y * (ww.y + aa.y * hb.y);
        sum += hh.z * (ww.z + aa.z * hb.z);
        sum += hh.w * (ww.w + aa.w * hb.w);
    }
#pragma unroll
    for (int off = 32; off > 0; off >>= 1)
        sum += __shfl_xor(sum, off, 64);
    if (lane == 0) rec[row] = sum;
}

// ---------------------------------------------------------------------------
// Kernel 2: per batch element b (one block of 512 threads, thread i = unit i):
//   hactiv[b,i] = tanh(inputs[b,:]@Wi[i,:] + bi[i] + rec[b,i])
//   activout[b,:], valueout[b], DAout[b] via block reductions
//   scale[b,i] = DAout[b] * hactiv[b,i]   (for the hebb update kernel)
// ---------------------------------------------------------------------------
__global__ __launch_bounds__(512) void act_kernel(
    const float* __restrict__ inputs,
    const float* __restrict__ Wi, const float* __restrict__ bi,
    const float* __restrict__ rec,
    const float* __restrict__ Wo, const float* __restrict__ bo,
    const float* __restrict__ Wv, const float* __restrict__ bv,
    const float* __restrict__ Wda, const float* __restrict__ bda,
    float* __restrict__ activout, float* __restrict__ valueout,
    float* __restrict__ daout, float* __restrict__ hactiv,
    float* __restrict__ scale)
{
    const int b = blockIdx.x;
    const int i = threadIdx.x;

    __shared__ __align__(16) float sh_in[IN_DIM];
    __shared__ float red[8][8];       // [wave][6 partial sums]
    __shared__ float da_sh;

    if (i < IN_DIM) sh_in[i] = inputs[b * IN_DIM + i];
    __syncthreads();

    // inputs[b,:] @ Wi[i,:]
    float dot = 0.f;
    const float4* __restrict__ wi4 = (const float4*)(Wi + (size_t)i * IN_DIM);
    const float4* __restrict__ in4 = (const float4*)sh_in;
#pragma unroll
    for (int t = 0; t < IN_DIM / 4; ++t) {
        const float4 a = wi4[t];
        const float4 x = in4[t];
        dot += a.x * x.x + a.y * x.y + a.z * x.z + a.w * x.w;
    }

    const float h = tanhf(dot + bi[i] + rec[(size_t)b * HS + i]);
    hactiv[(size_t)b * HS + i] = h;

    // six reductions over i: Wo rows 0..3, Wv, Wda
    float p[6];
    p[0] = h * Wo[0 * HS + i];
    p[1] = h * Wo[1 * HS + i];
    p[2] = h * Wo[2 * HS + i];
    p[3] = h * Wo[3 * HS + i];
    p[4] = h * Wv[i];
    p[5] = h * Wda[i];

    const int lane = i & 63, wave = i >> 6;
#pragma unroll
    for (int k = 0; k < 6; ++k) {
        float s = p[k];
#pragma unroll
        for (int off = 32; off > 0; off >>= 1)
            s += __shfl_xor(s, off, 64);
        if (lane == 0) red[wave][k] = s;
    }
    __syncthreads();

    if (i < 6) {
        float s = 0.f;
#pragma unroll
        for (int wv = 0; wv < 8; ++wv) s += red[wv][i];
        if (i < 4) {
            activout[b * OUT_DIM + i] = s + bo[i];
        } else if (i == 4) {
            valueout[b] = s + bv[0];
        } else {
            const float da = tanhf(s + bda[0]);
            daout[b] = da;
            da_sh = da;
        }
    }
    __syncthreads();

    scale[(size_t)b * HS + i] = da_sh * h;
}

// ---------------------------------------------------------------------------
// Kernel 3: hebb_new[b,i,j] = clip(hebb[b,i,j] + scale[b,i]*hidden[b,j], -1, 1)
// REVERSE-order streaming (tail of hebb is L3-resident after kernel 1's
// forward pass) + non-temporal stores so the 268 MB hebb_new write stream
// does not evict the hebb read-set from L3.
// ---------------------------------------------------------------------------
__global__ __launch_bounds__(256) void hebb_kernel(
    const float* __restrict__ hebb,
    const float* __restrict__ hidden,
    const float* __restrict__ scale,
    float* __restrict__ hebb_new)
{
    const long long total4 = (long long)BS * HS * HS / 4;    // 16,777,216
    const long long stride = (long long)gridDim.x * blockDim.x;
    const long long tid    = (long long)blockIdx.x * blockDim.x + threadIdx.x;
    for (long long v = total4 - 1 - tid; v >= 0; v -= stride) {
        const long long e = v * 4;
        const int b = (int)(e >> 18);            // / (HS*HS)
        const int i = (int)(e >> 9) & (HS - 1);  // / HS % HS
        const int j = (int)e & (HS - 1);         // % HS (multiple of 4)

        const float s = scale[b * HS + i];
        const float4 hid = *(const float4*)(hidden + b * HS + j);
        const float4 hb  = ((const float4*)hebb)[v];
        nfloat4 o;
        o.x = fminf(fmaxf(hb.x + s * hid.x, -1.f), 1.f);
        o.y = fminf(fmaxf(hb.y + s * hid.y, -1.f), 1.f);
        o.z = fminf(fmaxf(hb.z + s * hid.z, -1.f), 1.f);
        o.w = fminf(fmaxf(hb.w + s * hid.w, -1.f), 1.f);
        __builtin_nontemporal_store(o, (nfloat4*)hebb_new + v);
    }
}

extern "C" void kernel_launch(void* const* d_in, const int* in_sizes, int n_in,
                              void* d_out, int out_size, void* d_ws, size_t ws_size,
                              hipStream_t stream) {
    const float* inputs = (const float*)d_in[0];
    const float* hidden = (const float*)d_in[1];
    const float* hebb   = (const float*)d_in[2];
    const float* Wi     = (const float*)d_in[3];
    const float* bi     = (const float*)d_in[4];
    const float* w      = (const float*)d_in[5];
    const float* alpha  = (const float*)d_in[6];
    const float* Wo     = (const float*)d_in[7];
    const float* bo     = (const float*)d_in[8];
    const float* Wv     = (const float*)d_in[9];
    const float* bv     = (const float*)d_in[10];
    const float* Wda    = (const float*)d_in[11];
    const float* bda    = (const float*)d_in[12];

    float* out = (float*)d_out;
    float* activout = out;                       // [256,4]   = 1024
    float* valueout = out + 1024;                // [256,1]   = 256
    float* daout    = out + 1280;                // [256,1]   = 256
    float* hactiv   = out + 1536;                // [256,512] = 131072
    float* hebb_new = out + 1536 + BS * HS;      // [256,512,512]

    // workspace: rec and scale share the same 512 KB buffer (rec is consumed
    // by the same thread that later writes scale at the same index)
    float* rec   = (float*)d_ws;
    float* scale = rec;

    // Kernel 1: 131072 rows, 4 waves/block, forward order
    rec_kernel<<<(BS * HS) / 4, 256, 0, stream>>>(hidden, hebb, w, alpha, rec);

    // Kernel 2: one block per batch element
    act_kernel<<<BS, HS, 0, stream>>>(inputs, Wi, bi, rec, Wo, bo, Wv, bv,
                                      Wda, bda, activout, valueout, daout,
                                      hactiv, scale);

    // Kernel 3: streaming hebb update, reverse order + nt stores
    hebb_kernel<<<2048, 256, 0, stream>>>(hebb, hidden, scale, hebb_new);
}